// Round 9
// baseline (501.025 us; speedup 1.0000x reference)
//
#include <hip/hip_runtime.h>
#include <hip/hip_cooperative_groups.h>

namespace cg = cooperative_groups;

typedef unsigned short u16;
typedef unsigned int u32;
typedef __attribute__((ext_vector_type(8))) short short8;
typedef __attribute__((ext_vector_type(4))) float f32x4;

__device__ __forceinline__ u16 f2bf(float f) {
    unsigned u = __float_as_uint(f);
    return (u16)((u + 0x7FFFu + ((u >> 16) & 1u)) >> 16);  // RNE
}
__device__ __forceinline__ u32 pack2(float a, float b) {
    return ((u32)f2bf(b) << 16) | (u32)f2bf(a);
}

// ---- DPP row-rotate helpers (16-lane rows) ----
#define ROR1 0x121
#define ROR2 0x122
#define ROR4 0x124
#define ROR8 0x128
template<int C> __device__ __forceinline__ float dppf(float x) {
    int i = __float_as_int(x);
    return __int_as_float(__builtin_amdgcn_update_dpp(i, i, C, 0xF, 0xF, false));
}
template<int C> __device__ __forceinline__ int dppi(int x) {
    return __builtin_amdgcn_update_dpp(x, x, C, 0xF, 0xF, false);
}

// ---------------------------------------------------------------------------
// R7-proven GEMM body: C[64][c0..c0+128) over k-slice [k0,k0+kchunk).
// Depth-2 named-register pipeline (static indexing).  smem: 13568 B.
// SRC 0: A global bf16 [64][4096].  SRC 1: build X from emb (reshape quirk
//        X[r][e] = emb[2*(r&3)+(e>=128)][r>>2][e&127]; requires k0==0).
// EPI 0: fp32 partial -> Cp[slice].  EPI 1: bias+leaky -> bf16 Ho.
// nit = kchunk/32 must be EVEN.
// ---------------------------------------------------------------------------
template<int SRC, int EPI>
__device__ __forceinline__ void gemm_body(
    const u16* A, const float* emb, const float* W, const float* bias,
    float* Cp, u16* Ho, int N, int kchunk, int c0, int k0, int slice,
    char* smem, int tid)
{
    u16 (*Alds)[40] = (u16(*)[40])smem;            // 5120 B
    u32* Wlds = (u32*)(smem + 5120);               // 16*132 u32 = 8448 B
    int wv = tid >> 6, lane = tid & 63, c = lane & 15, g = lane >> 4;
    int nit = kchunk >> 5;
    int ar = tid >> 2, aseg = tid & 3;
    int kp = tid >> 4, cbase = (tid & 15) * 8;

    f32x4 acc[8];
    #pragma unroll
    for (int n = 0; n < 8; ++n) acc[n] = (f32x4){0.f, 0.f, 0.f, 0.f};

    auto loadA = [&](int kc, uint4& av) {
        if (SRC == 0) {
            av = *(const uint4*)(A + (size_t)ar * 4096 + k0 + kc + aseg * 8);
        } else {
            int e0 = kc + aseg * 8;
            int b = 2 * (ar & 3) + (e0 >> 7), d = e0 & 127;
            const float4* s = (const float4*)(emb + (b * 16 + (ar >> 2)) * 128 + d);
            float4 f0 = s[0], f1 = s[1];
            av.x = pack2(f0.x, f0.y); av.y = pack2(f0.z, f0.w);
            av.z = pack2(f1.x, f1.y); av.w = pack2(f1.z, f1.w);
        }
    };
    auto loadW = [&](int kc, float4& q0, float4& q1, float4& q2, float4& q3) {
        const float* s0 = W + (size_t)(k0 + kc + 2 * kp) * N + c0 + cbase;
        q0 = ((const float4*)s0)[0]; q1 = ((const float4*)s0)[1];
        const float* s1 = s0 + N;
        q2 = ((const float4*)s1)[0]; q3 = ((const float4*)s1)[1];
    };
    auto stage = [&](const uint4& av, const float4& q0, const float4& q1,
                     const float4& q2, const float4& q3) {
        *(uint4*)&Alds[ar][aseg * 8] = av;
        uint4 w0, w1;
        w0.x = pack2(q0.x, q2.x); w0.y = pack2(q0.y, q2.y);
        w0.z = pack2(q0.z, q2.z); w0.w = pack2(q0.w, q2.w);
        w1.x = pack2(q1.x, q3.x); w1.y = pack2(q1.y, q3.y);
        w1.z = pack2(q1.z, q3.z); w1.w = pack2(q1.w, q3.w);
        uint4* wd = (uint4*)&Wlds[kp * 132 + cbase];
        wd[0] = w0; wd[1] = w1;
    };
    auto compute = [&]() {
        short8 a8 = *(const short8*)&Alds[wv * 16 + c][g * 8];
        #pragma unroll
        for (int n = 0; n < 8; ++n) {
            int base = n * 16 + c;
            union { u32 u[4]; short8 s; } bb;
            bb.u[0] = Wlds[(g * 4 + 0) * 132 + base];
            bb.u[1] = Wlds[(g * 4 + 1) * 132 + base];
            bb.u[2] = Wlds[(g * 4 + 2) * 132 + base];
            bb.u[3] = Wlds[(g * 4 + 3) * 132 + base];
            acc[n] = __builtin_amdgcn_mfma_f32_16x16x32_bf16(a8, bb.s, acc[n], 0, 0, 0);
        }
    };

    uint4 avA, avB;
    float4 qA0, qA1, qA2, qA3, qB0, qB1, qB2, qB3;
    loadA(0, avA);  loadW(0, qA0, qA1, qA2, qA3);
    loadA(32, avB); loadW(32, qB0, qB1, qB2, qB3);

    for (int it = 0; it < nit; it += 2) {
        stage(avA, qA0, qA1, qA2, qA3);
        __syncthreads();
        if (it + 2 < nit) { loadA((it + 2) * 32, avA); loadW((it + 2) * 32, qA0, qA1, qA2, qA3); }
        compute();
        __syncthreads();

        stage(avB, qB0, qB1, qB2, qB3);
        __syncthreads();
        if (it + 3 < nit) { loadA((it + 3) * 32, avB); loadW((it + 3) * 32, qB0, qB1, qB2, qB3); }
        compute();
        __syncthreads();
    }

    #pragma unroll
    for (int n = 0; n < 8; ++n) {
        #pragma unroll
        for (int rr = 0; rr < 4; ++rr) {
            int grow = wv * 16 + g * 4 + rr;
            int gcol = c0 + n * 16 + c;
            float v = acc[n][rr];
            if (EPI == 0) {
                Cp[(size_t)slice * 64 * N + (size_t)grow * N + gcol] = v;
            } else {
                v += bias[gcol];
                v = (v >= 0.f) ? v : 0.01f * v;
                Ho[(size_t)grow * N + gcol] = f2bf(v);
            }
        }
    }
}

// ---------------------------------------------------------------------------
// Shared power-iteration helper: 16-lane-group DPP matvec, 50 iters.
// pl = this block's matrices in LDS (m_local*256 floats each), tid in [0,256).
// ---------------------------------------------------------------------------
__device__ __forceinline__ float power_iterate(const float* pl, int tid) {
    float Mr[8], Ms[8];
    int mb = (tid >> 4) * 256 + (tid & 15) * 16;
    int idx = tid & 15;
    #pragma unroll
    for (int k = 0; k < 8; ++k) { Mr[k] = pl[mb + idx]; idx = dppi<ROR1>(idx); }
    #pragma unroll
    for (int k = 0; k < 8; ++k) { Ms[k] = pl[mb + idx]; idx = dppi<ROR1>(idx); }

    float v = 1.0f;
    #pragma unroll 1
    for (int it = 0; it < 50; ++it) {
        float va = v, vb = dppf<ROR8>(v);
        float w = 0.f, w2 = 0.f;
        #pragma unroll
        for (int k = 0; k < 8; ++k) {
            w  = fmaf(Mr[k], va, w);
            w2 = fmaf(Ms[k], vb, w2);
            if (k < 7) { va = dppf<ROR1>(va); vb = dppf<ROR1>(vb); }
        }
        w += w2;
        if ((it & 7) == 7) {   // positive-sum renorm; scale cancels in output
            float s = w;
            s += dppf<ROR8>(s); s += dppf<ROR4>(s);
            s += dppf<ROR2>(s); s += dppf<ROR1>(s);
            w *= 1.0f / s;
        }
        v = w;
    }
    return v;
}

// ---------------------------------------------------------------------------
// Factored output reduction (proven R4 form).  256 threads, block-local.
// smem layout: w_lds[1024] | Ts_lds[2048] | Cmat[128] floats.
// ---------------------------------------------------------------------------
__device__ __forceinline__ void out_body(const float* wvec, const float* Ts,
                                         float* outp, char* smem, int tid) {
    float* w_lds  = (float*)smem;          // 4096 B
    float* Ts_lds = w_lds + 1024;          // 8192 B
    float* Cmat   = Ts_lds + 2048;         //  512 B
    ((float4*)w_lds)[tid]        = ((const float4*)wvec)[tid];
    ((float4*)Ts_lds)[tid]       = ((const float4*)Ts)[tid];
    ((float4*)Ts_lds)[256 + tid] = ((const float4*)Ts)[256 + tid];
    __syncthreads();
    if (tid < 128) {
        int b = tid >> 4, x = tid & 15;
        float s = 0.f;
        if (b < 4) {
            #pragma unroll
            for (int t = 0; t < 16; ++t) s += Ts_lds[(b * 16 + x) * 16 + t];
        } else {
            int j = b - 4;
            #pragma unroll
            for (int si = 0; si < 16; ++si)
                s += Ts_lds[(b * 16 + si) * 16 + x] / w_lds[(x * 4 + j) * 16 + si];
        }
        Cmat[b * 16 + x] = s;
    }
    __syncthreads();
    if (tid < 128) {
        int b = tid >> 4, n = tid & 15;
        float o = 0.f;
        if (b < 4) {
            #pragma unroll
            for (int si = 0; si < 16; ++si) {
                const float* wr = &w_lds[(si * 4 + b) * 16];
                o += wr[n] / wr[si] * Cmat[b * 16 + si];
            }
        } else {
            int j = b - 4;
            #pragma unroll
            for (int t = 0; t < 16; ++t)
                o += w_lds[(t * 4 + j) * 16 + n] * Cmat[b * 16 + t];
        }
        outp[b * 16 + n] = o;
    }
}

// ---------------------------------------------------------------------------
// Cooperative mega: 9 phases, 8 grid.syncs, zero launch gaps.
// grid = 32*KS x 256.  LDS 16896 B union.  bounds(256,2) -> 2 blocks/CU.
// ---------------------------------------------------------------------------
struct MegaP {
    const float *emb, *Ts, *W1, *b1, *W2, *b2, *W3, *b3, *W4, *b4;
    float* out;
    u16 *Ha, *Hb;
    float *pol, *wvec, *Cp;
};

template<int KS>
__global__ __launch_bounds__(256, 2) void mega(MegaP p)
{
    __shared__ __align__(16) char smem[16896];
    cg::grid_group grid = cg::this_grid();
    int bid = blockIdx.x, tid = threadIdx.x;
    const int NB = 32 * KS;
    const int KCH = 4096 / KS;

    // P0: L1 fused build-X + GEMM + epilogue -> Ha (32 blocks, K=256)
    if (bid < 32)
        gemm_body<1, 1>(nullptr, p.emb, p.W1, p.b1, nullptr, p.Ha,
                        4096, 256, bid * 128, 0, 0, smem, tid);
    grid.sync();

    // P1: L2 GEMM -> Cp
    gemm_body<0, 0>(p.Ha, nullptr, p.W2, nullptr, p.Cp, nullptr,
                    4096, KCH, (bid & 31) * 128, (bid >> 5) * KCH, bid >> 5, smem, tid);
    grid.sync();

    // P2: reduce + bias + leaky -> Hb
    for (int e = bid * 256 + tid; e < 262144; e += NB * 256) {
        float s = p.b2[e & 4095];
        #pragma unroll
        for (int k = 0; k < KS; ++k) s += p.Cp[(size_t)k * 262144 + e];
        s = (s >= 0.f) ? s : 0.01f * s;
        p.Hb[e] = f2bf(s);
    }
    grid.sync();

    // P3: L3 GEMM -> Cp
    gemm_body<0, 0>(p.Hb, nullptr, p.W3, nullptr, p.Cp, nullptr,
                    4096, KCH, (bid & 31) * 128, (bid >> 5) * KCH, bid >> 5, smem, tid);
    grid.sync();

    // P4: reduce -> Ha
    for (int e = bid * 256 + tid; e < 262144; e += NB * 256) {
        float s = p.b3[e & 4095];
        #pragma unroll
        for (int k = 0; k < KS; ++k) s += p.Cp[(size_t)k * 262144 + e];
        s = (s >= 0.f) ? s : 0.01f * s;
        p.Ha[e] = f2bf(s);
    }
    grid.sync();

    // P5: L4 GEMM (64 blocks: 2 col-tiles x 32 k-slices, kchunk=128, nit=4)
    if (bid < 64)
        gemm_body<0, 0>(p.Ha, nullptr, p.W4, nullptr, p.Cp, nullptr,
                        256, 128, (bid & 1) * 128, (bid >> 1) * 128, bid >> 1, smem, tid);
    grid.sync();

    // P6: L4 reduce + bias + leaky + sigmoid -> pol (16384 elems, 64 blocks)
    if (bid < 64) {
        int e = bid * 256 + tid;
        float s = p.b4[e & 255];
        #pragma unroll
        for (int k = 0; k < 32; ++k) s += p.Cp[(size_t)k * 16384 + e];
        s = (s >= 0.f) ? s : 0.01f * s;
        p.pol[e] = 1.0f / (1.0f + __expf(-s));
    }
    grid.sync();

    // P7: power iterations (4 blocks x 16 matrices each)
    if (bid < 4) {
        float* pl = (float*)smem;   // 16 KB: 16 matrices
        const float4* src = (const float4*)(p.pol + bid * 4096);
        float4* d4 = (float4*)pl;
        d4[tid * 4 + 0] = src[tid * 4 + 0];
        d4[tid * 4 + 1] = src[tid * 4 + 1];
        d4[tid * 4 + 2] = src[tid * 4 + 2];
        d4[tid * 4 + 3] = src[tid * 4 + 3];
        __syncthreads();
        float v = power_iterate(pl, tid);
        p.wvec[bid * 256 + tid] = v;   // == [(bid*16 + m)*16 + r]
        __syncthreads();
    }
    grid.sync();

    // P8: factored output (block 0)
    if (bid == 0)
        out_body(p.wvec, p.Ts, p.out, smem, tid);
}

// ===========================================================================
// Fallback: verbatim R7 chain (proven 79.6 us).
// ===========================================================================
template<int SRC, int EPI>
__global__ __launch_bounds__(256, 2) void k_gemm(
    const u16* __restrict__ A, const float* __restrict__ emb,
    const float* __restrict__ W, const float* __restrict__ bias,
    float* __restrict__ Cp, u16* __restrict__ Ho,
    int N, int kchunk)
{
    __shared__ __align__(16) char smem[13568];
    gemm_body<SRC, EPI>(A, emb, W, bias, Cp, Ho, N, kchunk,
                        blockIdx.x * 128, blockIdx.y * kchunk, blockIdx.y,
                        smem, threadIdx.x);
}

__global__ void k_reduce(const float* __restrict__ Cp, const float* __restrict__ bias,
                         u16* __restrict__ Hb, float* __restrict__ Pf,
                         int N, int ksplit, int mode)
{
    int idx = blockIdx.x * 256 + threadIdx.x;
    int col = idx & (N - 1);
    float s = bias[col];
    #pragma unroll 4
    for (int k = 0; k < ksplit; ++k) s += Cp[(size_t)k * 64 * N + idx];
    float a = (s >= 0.f) ? s : 0.01f * s;
    if (mode == 0) Hb[idx] = f2bf(a);
    else           Pf[idx] = 1.0f / (1.0f + __expf(-a));
}

__global__ __launch_bounds__(1024) void k_power_out(
    const float* __restrict__ pol, const float* __restrict__ Ts,
    float* __restrict__ out)
{
    __shared__ float pol_lds[16384];
    __shared__ __align__(16) char osmem[12800 + 512];
    __shared__ float wv_s[1024];
    int tid = threadIdx.x;
    {
        const float4* p4 = (const float4*)(pol + tid * 16);
        float4* q4 = (float4*)&pol_lds[tid * 16];
        q4[0] = p4[0]; q4[1] = p4[1]; q4[2] = p4[2]; q4[3] = p4[3];
    }
    __syncthreads();
    // 4 virtual 256-thread groups, each handling 16 matrices
    int grp = tid >> 8, t = tid & 255;
    float v = power_iterate(&pol_lds[grp * 4096], t);
    wv_s[tid] = v;
    __syncthreads();
    if (tid < 256) {
        // out_body expects wvec/Ts in global-like memory; wv_s is LDS: copy path
        // reuse same logic inline via pointers (LDS pointers work fine)
        out_body(wv_s, Ts, out, osmem, tid);
    }
}

// ---------------------------------------------------------------------------
extern "C" void kernel_launch(void* const* d_in, const int* in_sizes, int n_in,
                              void* d_out, int out_size, void* d_ws, size_t ws_size,
                              hipStream_t stream)
{
    const float* emb = (const float*)d_in[0];
    const float* Ts  = (const float*)d_in[2];
    const float* W1  = (const float*)d_in[3];  const float* b1 = (const float*)d_in[4];
    const float* W2  = (const float*)d_in[5];  const float* b2 = (const float*)d_in[6];
    const float* W3  = (const float*)d_in[7];  const float* b3 = (const float*)d_in[8];
    const float* W4  = (const float*)d_in[9];  const float* b4 = (const float*)d_in[10];
    float* outp = (float*)d_out;

    char* ws = (char*)d_ws;
    u16*   Ha   = (u16*)(ws + 0);             // 512 KB
    u16*   Hb   = (u16*)(ws + 524288);        // 512 KB
    float* pol  = (float*)(ws + 1048576);     //  64 KB
    float* wvec = (float*)(ws + 1114112);     //   4 KB
    float* Cp   = (float*)(ws + 1118208);     //  KS MB fp32 partials

    size_t need16 = (size_t)1118208 + (size_t)16 * 1048576;
    int KS = (ws_size >= need16) ? 16 : 8;
    int kchunk = 4096 / KS;

    MegaP prm { emb, Ts, W1, b1, W2, b2, W3, b3, W4, b4, outp, Ha, Hb, pol, wvec, Cp };

    bool coop = false;
    int nb = 0;
    if (KS == 16) {
        hipError_t qe = hipOccupancyMaxActiveBlocksPerMultiprocessor(&nb, mega<16>, 256, 0);
        coop = (qe == hipSuccess && nb >= 2);
        if (coop) {
            void* args[] = { &prm };
            coop = (hipLaunchCooperativeKernel((const void*)mega<16>, dim3(512), dim3(256),
                                               args, 0, stream) == hipSuccess);
        }
    } else {
        hipError_t qe = hipOccupancyMaxActiveBlocksPerMultiprocessor(&nb, mega<8>, 256, 0);
        coop = (qe == hipSuccess && nb >= 1);
        if (coop) {
            void* args[] = { &prm };
            coop = (hipLaunchCooperativeKernel((const void*)mega<8>, dim3(256), dim3(256),
                                               args, 0, stream) == hipSuccess);
        }
    }

    if (!coop) {   // proven R7 chain
        k_gemm<1, 1><<<dim3(32, 1), 256, 0, stream>>>(
            nullptr, emb, W1, b1, nullptr, Ha, 4096, 256);
        k_gemm<0, 0><<<dim3(32, KS), 256, 0, stream>>>(
            Ha, nullptr, W2, nullptr, Cp, nullptr, 4096, kchunk);
        k_reduce<<<1024, 256, 0, stream>>>(Cp, b2, Hb, nullptr, 4096, KS, 0);
        k_gemm<0, 0><<<dim3(32, KS), 256, 0, stream>>>(
            Hb, nullptr, W3, nullptr, Cp, nullptr, 4096, kchunk);
        k_reduce<<<1024, 256, 0, stream>>>(Cp, b3, Ha, nullptr, 4096, KS, 0);
        k_gemm<0, 0><<<dim3(2, 32), 256, 0, stream>>>(
            Ha, nullptr, W4, nullptr, Cp, nullptr, 256, 128);
        k_reduce<<<64, 256, 0, stream>>>(Cp, b4, nullptr, pol, 256, 32, 1);
        k_power_out<<<1, 1024, 0, stream>>>(pol, Ts, outp);
    }

    (void)in_sizes; (void)n_in; (void)out_size; (void)ws_size;
}

// Round 10
// 280.246 us; speedup vs baseline: 1.7878x; 1.7878x over previous
//
#include <hip/hip_runtime.h>

typedef unsigned short u16;
typedef unsigned int u32;
typedef __attribute__((ext_vector_type(8))) short short8;
typedef __attribute__((ext_vector_type(4))) float f32x4;

__device__ __forceinline__ u16 f2bf(float f) {
    unsigned u = __float_as_uint(f);
    return (u16)((u + 0x7FFFu + ((u >> 16) & 1u)) >> 16);  // RNE
}
__device__ __forceinline__ u32 pack2(float a, float b) {
    return ((u32)f2bf(b) << 16) | (u32)f2bf(a);
}
__device__ __forceinline__ float bfhi(u32 w) { return __uint_as_float(w & 0xFFFF0000u); }
__device__ __forceinline__ float bflo(u32 w) { return __uint_as_float(w << 16); }

// ---- DPP row-rotate helpers (16-lane rows) ----
#define ROR1 0x121
#define ROR2 0x122
#define ROR4 0x124
#define ROR8 0x128
template<int C> __device__ __forceinline__ float dppf(float x) {
    int i = __float_as_int(x);
    return __int_as_float(__builtin_amdgcn_update_dpp(i, i, C, 0xF, 0xF, false));
}
template<int C> __device__ __forceinline__ int dppi(int x) {
    return __builtin_amdgcn_update_dpp(x, x, C, 0xF, 0xF, false);
}

// ---------------------------------------------------------------------------
// R7-proven GEMM core: acc[8] = A[64][k0:k0+kchunk] @ W[k0:k0+kchunk][c0:c0+128)
// Depth-2 named-register pipeline, static indexing.  smem: 13568 B.
// SRC 0: A global bf16 [64][4096].  SRC 1: build X from emb (reshape quirk
//        X[r][e] = emb[2*(r&3)+(e>=128)][r>>2][e&127]; requires k0==0).
// nit = kchunk/32 must be EVEN.
// ---------------------------------------------------------------------------
template<int SRC>
__device__ __forceinline__ void gemm_core(
    const u16* __restrict__ A, const float* __restrict__ emb,
    const float* __restrict__ W, int N, int kchunk, int c0, int k0,
    char* smem, int tid, f32x4* acc)
{
    u16 (*Alds)[40] = (u16(*)[40])smem;            // 5120 B
    u32* Wlds = (u32*)(smem + 5120);               // 16*132 u32 = 8448 B
    int wv = tid >> 6, lane = tid & 63, c = lane & 15, g = lane >> 4;
    int nit = kchunk >> 5;
    int ar = tid >> 2, aseg = tid & 3;
    int kp = tid >> 4, cbase = (tid & 15) * 8;

    #pragma unroll
    for (int n = 0; n < 8; ++n) acc[n] = (f32x4){0.f, 0.f, 0.f, 0.f};

    auto loadA = [&](int kc, uint4& av) {
        if (SRC == 0) {
            av = *(const uint4*)(A + (size_t)ar * 4096 + k0 + kc + aseg * 8);
        } else {
            int e0 = kc + aseg * 8;
            int b = 2 * (ar & 3) + (e0 >> 7), d = e0 & 127;
            const float4* s = (const float4*)(emb + (b * 16 + (ar >> 2)) * 128 + d);
            float4 f0 = s[0], f1 = s[1];
            av.x = pack2(f0.x, f0.y); av.y = pack2(f0.z, f0.w);
            av.z = pack2(f1.x, f1.y); av.w = pack2(f1.z, f1.w);
        }
    };
    auto loadW = [&](int kc, float4& q0, float4& q1, float4& q2, float4& q3) {
        const float* s0 = W + (size_t)(k0 + kc + 2 * kp) * N + c0 + cbase;
        q0 = ((const float4*)s0)[0]; q1 = ((const float4*)s0)[1];
        const float* s1 = s0 + N;
        q2 = ((const float4*)s1)[0]; q3 = ((const float4*)s1)[1];
    };
    auto stage = [&](const uint4& av, const float4& q0, const float4& q1,
                     const float4& q2, const float4& q3) {
        *(uint4*)&Alds[ar][aseg * 8] = av;
        uint4 w0, w1;
        w0.x = pack2(q0.x, q2.x); w0.y = pack2(q0.y, q2.y);
        w0.z = pack2(q0.z, q2.z); w0.w = pack2(q0.w, q2.w);
        w1.x = pack2(q1.x, q3.x); w1.y = pack2(q1.y, q3.y);
        w1.z = pack2(q1.z, q3.z); w1.w = pack2(q1.w, q3.w);
        uint4* wd = (uint4*)&Wlds[kp * 132 + cbase];
        wd[0] = w0; wd[1] = w1;
    };
    auto compute = [&]() {
        short8 a8 = *(const short8*)&Alds[wv * 16 + c][g * 8];
        #pragma unroll
        for (int n = 0; n < 8; ++n) {
            int base = n * 16 + c;
            union { u32 u[4]; short8 s; } bb;
            bb.u[0] = Wlds[(g * 4 + 0) * 132 + base];
            bb.u[1] = Wlds[(g * 4 + 1) * 132 + base];
            bb.u[2] = Wlds[(g * 4 + 2) * 132 + base];
            bb.u[3] = Wlds[(g * 4 + 3) * 132 + base];
            acc[n] = __builtin_amdgcn_mfma_f32_16x16x32_bf16(a8, bb.s, acc[n], 0, 0, 0);
        }
    };

    uint4 avA, avB;
    float4 qA0, qA1, qA2, qA3, qB0, qB1, qB2, qB3;
    loadA(0, avA);  loadW(0, qA0, qA1, qA2, qA3);
    loadA(32, avB); loadW(32, qB0, qB1, qB2, qB3);

    for (int it = 0; it < nit; it += 2) {
        stage(avA, qA0, qA1, qA2, qA3);
        __syncthreads();
        if (it + 2 < nit) { loadA((it + 2) * 32, avA); loadW((it + 2) * 32, qA0, qA1, qA2, qA3); }
        compute();
        __syncthreads();

        stage(avB, qB0, qB1, qB2, qB3);
        __syncthreads();
        if (it + 3 < nit) { loadA((it + 3) * 32, avB); loadW((it + 3) * 32, qB0, qB1, qB2, qB3); }
        compute();
        __syncthreads();
    }
}

// ---------------------------------------------------------------------------
// L1: fused build-X + GEMM + bias + leaky -> bf16 Ha.  grid (32,1).
// ---------------------------------------------------------------------------
__global__ __launch_bounds__(256, 2) void k_l1(
    const float* __restrict__ emb, const float* __restrict__ W,
    const float* __restrict__ bias, u16* __restrict__ Ho)
{
    __shared__ __align__(16) char smem[13568];
    int tid = threadIdx.x;
    f32x4 acc[8];
    gemm_core<1>(nullptr, emb, W, 4096, 256, blockIdx.x * 128, 0, smem, tid, acc);
    int wv = tid >> 6, lane = tid & 63, c = lane & 15, g = lane >> 4;
    int c0 = blockIdx.x * 128;
    #pragma unroll
    for (int n = 0; n < 8; ++n) {
        #pragma unroll
        for (int rr = 0; rr < 4; ++rr) {
            int grow = wv * 16 + g * 4 + rr;
            int gcol = c0 + n * 16 + c;
            float v = acc[n][rr] + bias[gcol];
            v = (v >= 0.f) ? v : 0.01f * v;
            Ho[(size_t)grow * 4096 + gcol] = f2bf(v);
        }
    }
}

// ---------------------------------------------------------------------------
// Split-K GEMM with counter fixup: grid (N/128, KS).  Each block writes its
// bf16 partial tile [64][128] contiguously at Cp16[(cx*KS+ky)*8192], then
// threadfence + atomicAdd(cnt[cx]); the LAST block per column-tile reduces
// all KS slices, applies bias + leaky (+ sigmoid for EPI=1) and stores.
// EPI 0 -> bf16 Ho;  EPI 1 -> fp32 Po (pol).
// ---------------------------------------------------------------------------
template<int EPI>
__global__ __launch_bounds__(256, 2) void k_gemm_fix(
    const u16* __restrict__ A, const float* __restrict__ W,
    const float* __restrict__ bias, u16* __restrict__ Cp16,
    int* __restrict__ cnt, u16* __restrict__ Ho, float* __restrict__ Po,
    int N, int kchunk, int KS)
{
    __shared__ __align__(16) char smem[13568];
    __shared__ int s_last;
    int tid = threadIdx.x;
    int cx = blockIdx.x, ky = blockIdx.y;
    int c0 = cx * 128;
    f32x4 acc[8];
    gemm_core<0>(A, nullptr, W, N, kchunk, c0, ky * kchunk, smem, tid, acc);

    // ---- write bf16 partial, tile-contiguous
    u16* slice = Cp16 + (size_t)(cx * KS + ky) * 8192;
    int wv = tid >> 6, lane = tid & 63, c = lane & 15, g = lane >> 4;
    #pragma unroll
    for (int n = 0; n < 8; ++n) {
        #pragma unroll
        for (int rr = 0; rr < 4; ++rr) {
            int grow = wv * 16 + g * 4 + rr;
            slice[grow * 128 + n * 16 + c] = f2bf(acc[n][rr]);
        }
    }
    __threadfence();                 // release this block's partial (device scope)
    __syncthreads();
    if (tid == 0) s_last = (atomicAdd(&cnt[cx], 1) == KS - 1);
    __syncthreads();
    if (!s_last) return;
    __threadfence();                 // acquire other blocks' partials

    // ---- fixup: reduce KS slices of tile [64][128], bias+act, store
    const u16* base = Cp16 + (size_t)cx * KS * 8192;
    #pragma unroll
    for (int j = 0; j < 4; ++j) {
        int e0 = (tid + j * 256) * 8;          // 8 consecutive elems
        float s[8];
        #pragma unroll
        for (int q = 0; q < 8; ++q) s[q] = 0.f;
        for (int k = 0; k < KS; ++k) {
            uint4 w4 = *(const uint4*)(base + (size_t)k * 8192 + e0);
            s[0] += bflo(w4.x); s[1] += bfhi(w4.x);
            s[2] += bflo(w4.y); s[3] += bfhi(w4.y);
            s[4] += bflo(w4.z); s[5] += bfhi(w4.z);
            s[6] += bflo(w4.w); s[7] += bfhi(w4.w);
        }
        int row = e0 >> 7, colin = e0 & 127;
        #pragma unroll
        for (int q = 0; q < 8; ++q) {
            float a = s[q] + bias[c0 + colin + q];
            a = (a >= 0.f) ? a : 0.01f * a;
            if (EPI == 0) Ho[(size_t)row * N + c0 + colin + q] = f2bf(a);
            else          Po[(size_t)row * N + c0 + colin + q] = 1.0f / (1.0f + __expf(-a));
        }
    }
}

// ---------------------------------------------------------------------------
// 50 power iterations (VALU/DPP only) + factored output reduction.  Proven.
// ---------------------------------------------------------------------------
__global__ __launch_bounds__(1024) void k_power_out(
    const float* __restrict__ pol,  // [64][16][16] fp32 (post-sigmoid)
    const float* __restrict__ Ts,   // [8][16][16]
    float* __restrict__ out)        // [8][16]
{
    __shared__ float pol_lds[16384];
    __shared__ float w_lds[64][16];
    __shared__ float Ts_lds[2048];
    __shared__ float Cmat[8][16];

    int tid = threadIdx.x;
    int m = tid >> 4, r = tid & 15;

    {
        const float4* p4 = (const float4*)(pol + tid * 16);
        float4* q4 = (float4*)&pol_lds[tid * 16];
        q4[0] = p4[0]; q4[1] = p4[1]; q4[2] = p4[2]; q4[3] = p4[3];
    }
    Ts_lds[tid] = Ts[tid];
    Ts_lds[tid + 1024] = Ts[tid + 1024];
    __syncthreads();

    float Mr[8], Ms[8];
    {
        int mb = m * 256 + r * 16;
        int idx = r;
        #pragma unroll
        for (int k = 0; k < 8; ++k) { Mr[k] = pol_lds[mb + idx]; idx = dppi<ROR1>(idx); }
        #pragma unroll
        for (int k = 0; k < 8; ++k) { Ms[k] = pol_lds[mb + idx]; idx = dppi<ROR1>(idx); }
    }

    float v = 1.0f;
    #pragma unroll 1
    for (int it = 0; it < 50; ++it) {
        float va = v, vb = dppf<ROR8>(v);
        float w = 0.f, w2 = 0.f;
        #pragma unroll
        for (int k = 0; k < 8; ++k) {
            w  = fmaf(Mr[k], va, w);
            w2 = fmaf(Ms[k], vb, w2);
            if (k < 7) { va = dppf<ROR1>(va); vb = dppf<ROR1>(vb); }
        }
        w += w2;
        if ((it & 7) == 7) {   // positive-sum renorm; scale cancels in output
            float s = w;
            s += dppf<ROR8>(s); s += dppf<ROR4>(s);
            s += dppf<ROR2>(s); s += dppf<ROR1>(s);
            w *= 1.0f / s;
        }
        v = w;
    }
    w_lds[m][r] = v;
    __syncthreads();

    if (tid < 128) {
        int b = tid >> 4, x = tid & 15;
        float s = 0.f;
        if (b < 4) {
            #pragma unroll
            for (int t = 0; t < 16; ++t) s += Ts_lds[(b * 16 + x) * 16 + t];
        } else {
            int j = b - 4;
            #pragma unroll
            for (int si = 0; si < 16; ++si)
                s += Ts_lds[(b * 16 + si) * 16 + x] / w_lds[x * 4 + j][si];
        }
        Cmat[b][x] = s;
    }
    __syncthreads();

    if (tid < 128) {
        int b = tid >> 4, n = tid & 15;
        float o = 0.f;
        if (b < 4) {
            #pragma unroll
            for (int si = 0; si < 16; ++si) {
                const float* wr = w_lds[si * 4 + b];
                o += wr[n] / wr[si] * Cmat[b][si];
            }
        } else {
            int j = b - 4;
            #pragma unroll
            for (int t = 0; t < 16; ++t)
                o += w_lds[t * 4 + j][n] * Cmat[b][t];
        }
        out[b * 16 + n] = o;
    }
}

// ---------------------------------------------------------------------------
extern "C" void kernel_launch(void* const* d_in, const int* in_sizes, int n_in,
                              void* d_out, int out_size, void* d_ws, size_t ws_size,
                              hipStream_t stream)
{
    const float* emb = (const float*)d_in[0];
    const float* Ts  = (const float*)d_in[2];
    const float* W1  = (const float*)d_in[3];  const float* b1 = (const float*)d_in[4];
    const float* W2  = (const float*)d_in[5];  const float* b2 = (const float*)d_in[6];
    const float* W3  = (const float*)d_in[7];  const float* b3 = (const float*)d_in[8];
    const float* W4  = (const float*)d_in[9];  const float* b4 = (const float*)d_in[10];
    float* outp = (float*)d_out;

    char* ws = (char*)d_ws;
    u16*   Ha  = (u16*)(ws + 0);            // 512 KB  [64][4096] bf16
    u16*   Hb  = (u16*)(ws + 524288);       // 512 KB  [64][4096] bf16
    float* pol = (float*)(ws + 1048576);    //  64 KB  [64][16][16] fp32
    int*   cnt = (int*)(ws + 1114112);      //   4 KB  fixup counters
    u16*   Cp  = (u16*)(ws + 1118208);      //  KS/2 MB bf16 partials

    // adaptive ksplit for mids: 16 if workspace permits (Cp = KS*512 KB)
    size_t need16 = (size_t)1118208 + (size_t)16 * 524288;   // ~9.5 MB
    int KS = (ws_size >= need16) ? 16 : 8;
    int kchunk = 4096 / KS;

    // zero fixup counters (stream-ordered; re-runs on every graph replay)
    hipMemsetAsync(cnt, 0, 4096, stream);

    // L1: fused build-X + GEMM -> Ha
    k_l1<<<dim3(32, 1), 256, 0, stream>>>(emb, W1, b1, Ha);

    // L2: split-K + fixup -> Hb
    k_gemm_fix<0><<<dim3(32, KS), 256, 0, stream>>>(
        Ha, W2, b2, Cp, cnt + 0, Hb, nullptr, 4096, kchunk, KS);

    // L3: split-K + fixup -> Ha
    k_gemm_fix<0><<<dim3(32, KS), 256, 0, stream>>>(
        Hb, W3, b3, Cp, cnt + 32, Ha, nullptr, 4096, kchunk, KS);

    // L4: N=256, split-K KS=32 (kchunk=128, nit=4) + fixup + sigmoid -> pol
    k_gemm_fix<1><<<dim3(2, 32), 256, 0, stream>>>(
        Ha, W4, b4, Cp, cnt + 64, nullptr, pol, 256, 128, 32);

    // Power iteration + factored output
    k_power_out<<<1, 1024, 0, stream>>>(pol, Ts, outp);

    (void)in_sizes; (void)n_in; (void)out_size; (void)ws_size;
}

// Round 11
// 75.219 us; speedup vs baseline: 6.6608x; 3.7257x over previous
//
#include <hip/hip_runtime.h>

typedef unsigned short u16;
typedef unsigned int u32;
typedef __attribute__((ext_vector_type(8))) short short8;
typedef __attribute__((ext_vector_type(4))) float f32x4;

__device__ __forceinline__ u16 f2bf(float f) {
    unsigned u = __float_as_uint(f);
    return (u16)((u + 0x7FFFu + ((u >> 16) & 1u)) >> 16);  // RNE
}
__device__ __forceinline__ u32 pack2(float a, float b) {
    return ((u32)f2bf(b) << 16) | (u32)f2bf(a);
}
__device__ __forceinline__ float bf2f(u16 w) { return __uint_as_float((u32)w << 16); }

// ---- DPP row-rotate helpers (16-lane rows) ----
#define ROR1 0x121
#define ROR2 0x122
#define ROR4 0x124
#define ROR8 0x128
template<int C> __device__ __forceinline__ float dppf(float x) {
    int i = __float_as_int(x);
    return __int_as_float(__builtin_amdgcn_update_dpp(i, i, C, 0xF, 0xF, false));
}
template<int C> __device__ __forceinline__ int dppi(int x) {
    return __builtin_amdgcn_update_dpp(x, x, C, 0xF, 0xF, false);
}

// ---------------------------------------------------------------------------
// R7-proven unified GEMM: C[64][c0..c0+128) over k-slice [k0,k0+kchunk).
// grid (N/128, KS), 256 threads.  Depth-2 named-register pipeline (static
// indexing), __launch_bounds__(256,2).  W read: threads 0..15 cover one full
// 512B row segment (coalesced); W LDS k-pair-major [kp][132] u32.
// SRC 0: A global bf16 [64][4096].  SRC 1: build X from emb (reshape quirk
//        X[r][e] = emb[2*(r&3)+(e>=128)][r>>2][e&127]).
// EPI 0: bf16 partial -> Cp16[slice].  EPI 1: bias+leaky -> bf16 Ho.
// nit = kchunk/32 must be EVEN.
// ---------------------------------------------------------------------------
template<int SRC, int EPI>
__global__ __launch_bounds__(256, 2) void k_gemm(
    const u16* __restrict__ A, const float* __restrict__ emb,
    const float* __restrict__ W, const float* __restrict__ bias,
    u16* __restrict__ Cp16, u16* __restrict__ Ho,
    int N, int kchunk)
{
    __shared__ __align__(16) u16 Alds[64][40];     // 5120 B
    __shared__ __align__(16) u32 Wlds[16 * 132];   // 8448 B
    int tid = threadIdx.x;
    int wv = tid >> 6, lane = tid & 63, c = lane & 15, g = lane >> 4;
    int c0 = blockIdx.x * 128;
    int k0 = blockIdx.y * kchunk;
    int nit = kchunk >> 5;

    int ar = tid >> 2, aseg = tid & 3;          // A staging: row, 8-elem seg
    int kp = tid >> 4, cbase = (tid & 15) * 8;  // W staging: k-pair, col base

    f32x4 acc[8];
    #pragma unroll
    for (int n = 0; n < 8; ++n) acc[n] = (f32x4){0.f, 0.f, 0.f, 0.f};

    auto loadA = [&](int kc, uint4& av) {
        if (SRC == 0) {
            av = *(const uint4*)(A + (size_t)ar * 4096 + k0 + kc + aseg * 8);
        } else {
            int e0 = kc + aseg * 8;
            int b = 2 * (ar & 3) + (e0 >> 7), d = e0 & 127;
            const float4* s = (const float4*)(emb + (b * 16 + (ar >> 2)) * 128 + d);
            float4 f0 = s[0], f1 = s[1];
            av.x = pack2(f0.x, f0.y); av.y = pack2(f0.z, f0.w);
            av.z = pack2(f1.x, f1.y); av.w = pack2(f1.z, f1.w);
        }
    };
    auto loadW = [&](int kc, float4& q0, float4& q1, float4& q2, float4& q3) {
        const float* s0 = W + (size_t)(k0 + kc + 2 * kp) * N + c0 + cbase;
        q0 = ((const float4*)s0)[0]; q1 = ((const float4*)s0)[1];
        const float* s1 = s0 + N;
        q2 = ((const float4*)s1)[0]; q3 = ((const float4*)s1)[1];
    };
    auto stage = [&](const uint4& av, const float4& q0, const float4& q1,
                     const float4& q2, const float4& q3) {
        *(uint4*)&Alds[ar][aseg * 8] = av;
        uint4 w0, w1;
        w0.x = pack2(q0.x, q2.x); w0.y = pack2(q0.y, q2.y);
        w0.z = pack2(q0.z, q2.z); w0.w = pack2(q0.w, q2.w);
        w1.x = pack2(q1.x, q3.x); w1.y = pack2(q1.y, q3.y);
        w1.z = pack2(q1.z, q3.z); w1.w = pack2(q1.w, q3.w);
        uint4* wd = (uint4*)&Wlds[kp * 132 + cbase];
        wd[0] = w0; wd[1] = w1;
    };
    auto compute = [&]() {
        short8 a8 = *(const short8*)&Alds[wv * 16 + c][g * 8];
        #pragma unroll
        for (int n = 0; n < 8; ++n) {
            int base = n * 16 + c;
            union { u32 u[4]; short8 s; } bb;
            bb.u[0] = Wlds[(g * 4 + 0) * 132 + base];
            bb.u[1] = Wlds[(g * 4 + 1) * 132 + base];
            bb.u[2] = Wlds[(g * 4 + 2) * 132 + base];
            bb.u[3] = Wlds[(g * 4 + 3) * 132 + base];
            acc[n] = __builtin_amdgcn_mfma_f32_16x16x32_bf16(a8, bb.s, acc[n], 0, 0, 0);
        }
    };

    // ---- depth-2 pipeline, two named register sets (static indexing)
    uint4 avA, avB;
    float4 qA0, qA1, qA2, qA3, qB0, qB1, qB2, qB3;
    loadA(0, avA);  loadW(0, qA0, qA1, qA2, qA3);
    loadA(32, avB); loadW(32, qB0, qB1, qB2, qB3);

    for (int it = 0; it < nit; it += 2) {
        stage(avA, qA0, qA1, qA2, qA3);
        __syncthreads();
        if (it + 2 < nit) { loadA((it + 2) * 32, avA); loadW((it + 2) * 32, qA0, qA1, qA2, qA3); }
        compute();
        __syncthreads();

        stage(avB, qB0, qB1, qB2, qB3);
        __syncthreads();
        if (it + 3 < nit) { loadA((it + 3) * 32, avB); loadW((it + 3) * 32, qB0, qB1, qB2, qB3); }
        compute();
        __syncthreads();
    }

    // ---- epilogue (D layout: col = lane&15, row = g*4+rr)
    #pragma unroll
    for (int n = 0; n < 8; ++n) {
        #pragma unroll
        for (int rr = 0; rr < 4; ++rr) {
            int grow = wv * 16 + g * 4 + rr;
            int gcol = c0 + n * 16 + c;
            float v = acc[n][rr];
            if (EPI == 0) {
                Cp16[(size_t)blockIdx.y * 64 * N + (size_t)grow * N + gcol] = f2bf(v);
            } else {
                v += bias[gcol];
                v = (v >= 0.f) ? v : 0.01f * v;
                Ho[(size_t)grow * N + gcol] = f2bf(v);
            }
        }
    }
}

// ---------------------------------------------------------------------------
// Reduce bf16 split-K partials + bias + leaky; mode 0 -> bf16 H, mode 1 ->
// sigmoid(leaky) fp32.  grid = 64*N/256.
// ---------------------------------------------------------------------------
__global__ void k_reduce(const u16* __restrict__ Cp16, const float* __restrict__ bias,
                         u16* __restrict__ Hb, float* __restrict__ Pf,
                         int N, int ksplit, int mode)
{
    int idx = blockIdx.x * 256 + threadIdx.x;
    int col = idx & (N - 1);
    float s = bias[col];
    #pragma unroll 4
    for (int k = 0; k < ksplit; ++k) s += bf2f(Cp16[(size_t)k * 64 * N + idx]);
    float a = (s >= 0.f) ? s : 0.01f * s;
    if (mode == 0) Hb[idx] = f2bf(a);
    else           Pf[idx] = 1.0f / (1.0f + __expf(-a));
}

// ---------------------------------------------------------------------------
// 50 power iterations (VALU/DPP only) + factored output reduction.  Proven.
// ---------------------------------------------------------------------------
__global__ __launch_bounds__(1024) void k_power_out(
    const float* __restrict__ pol,  // [64][16][16] fp32 (post-sigmoid)
    const float* __restrict__ Ts,   // [8][16][16]
    float* __restrict__ out)        // [8][16]
{
    __shared__ float pol_lds[16384];
    __shared__ float w_lds[64][16];
    __shared__ float Ts_lds[2048];
    __shared__ float Cmat[8][16];

    int tid = threadIdx.x;
    int m = tid >> 4, r = tid & 15;

    {   // stage all 64 matrices (64 KB) to LDS
        const float4* p4 = (const float4*)(pol + tid * 16);
        float4* q4 = (float4*)&pol_lds[tid * 16];
        q4[0] = p4[0]; q4[1] = p4[1]; q4[2] = p4[2]; q4[3] = p4[3];
    }
    Ts_lds[tid] = Ts[tid];
    Ts_lds[tid + 1024] = Ts[tid + 1024];
    __syncthreads();

    // gather row r of matrix m with DPP-rotated index (matches va rotation)
    float Mr[8], Ms[8];
    {
        int mb = m * 256 + r * 16;
        int idx = r;
        #pragma unroll
        for (int k = 0; k < 8; ++k) { Mr[k] = pol_lds[mb + idx]; idx = dppi<ROR1>(idx); }
        #pragma unroll
        for (int k = 0; k < 8; ++k) { Ms[k] = pol_lds[mb + idx]; idx = dppi<ROR1>(idx); }
    }

    float v = 1.0f;
    #pragma unroll 1
    for (int it = 0; it < 50; ++it) {
        float va = v, vb = dppf<ROR8>(v);
        float w = 0.f, w2 = 0.f;
        #pragma unroll
        for (int k = 0; k < 8; ++k) {
            w  = fmaf(Mr[k], va, w);
            w2 = fmaf(Ms[k], vb, w2);
            if (k < 7) { va = dppf<ROR1>(va); vb = dppf<ROR1>(vb); }
        }
        w += w2;
        if ((it & 7) == 7) {   // positive-sum renorm; scale cancels in output
            float s = w;
            s += dppf<ROR8>(s); s += dppf<ROR4>(s);
            s += dppf<ROR2>(s); s += dppf<ROR1>(s);
            w *= 1.0f / s;
        }
        v = w;
    }
    w_lds[m][r] = v;
    __syncthreads();

    if (tid < 128) {
        int b = tid >> 4, x = tid & 15;
        float s = 0.f;
        if (b < 4) {                             // R[b][s=x] = sum_t Ts[b][x][t]
            const float* row = &Ts_lds[(b * 16 + x) * 16];
            #pragma unroll
            for (int t = 0; t < 16; ++t) s += row[t];
        } else {                                 // C[b][t=x]
            int j = b - 4;
            #pragma unroll
            for (int si = 0; si < 16; ++si)
                s += Ts_lds[(b * 16 + si) * 16 + x] / w_lds[x * 4 + j][si];
        }
        Cmat[b][x] = s;
    }
    __syncthreads();

    if (tid < 128) {
        int b = tid >> 4, n = tid & 15;
        float o = 0.f;
        if (b < 4) {
            #pragma unroll
            for (int si = 0; si < 16; ++si) {
                const float* wr = w_lds[si * 4 + b];
                o += wr[n] / wr[si] * Cmat[b][si];
            }
        } else {
            int j = b - 4;
            #pragma unroll
            for (int t = 0; t < 16; ++t)
                o += w_lds[t * 4 + j][n] * Cmat[b][t];
        }
        out[b * 16 + n] = o;
    }
}

// ---------------------------------------------------------------------------
extern "C" void kernel_launch(void* const* d_in, const int* in_sizes, int n_in,
                              void* d_out, int out_size, void* d_ws, size_t ws_size,
                              hipStream_t stream)
{
    const float* emb = (const float*)d_in[0];
    const float* Ts  = (const float*)d_in[2];
    const float* W1  = (const float*)d_in[3];  const float* b1 = (const float*)d_in[4];
    const float* W2  = (const float*)d_in[5];  const float* b2 = (const float*)d_in[6];
    const float* W3  = (const float*)d_in[7];  const float* b3 = (const float*)d_in[8];
    const float* W4  = (const float*)d_in[9];  const float* b4 = (const float*)d_in[10];
    float* outp = (float*)d_out;

    char* ws = (char*)d_ws;
    u16*   Ha  = (u16*)(ws + 0);            // 512 KB  [64][4096] bf16
    u16*   Hb  = (u16*)(ws + 524288);       // 512 KB  [64][4096] bf16
    float* pol = (float*)(ws + 1048576);    //  64 KB  [64][16][16] fp32
    u16*   Cp  = (u16*)(ws + 1114112);      //  bf16 split-K partials (KS*512 KB)

    // adaptive mid-layer ksplit: 16 if workspace permits (bf16: KS*512 KB)
    size_t need16 = (size_t)1114112 + (size_t)16 * 524288;   // ~9.5 MB
    int KS = (ws_size >= need16) ? 16 : 8;
    int kchunk = 4096 / KS;

    // L1: fused build-X + GEMM + epilogue -> Ha   (K=256, full-K, nit=8)
    k_gemm<1, 1><<<dim3(32, 1), 256, 0, stream>>>(
        nullptr, emb, W1, b1, nullptr, Ha, 4096, 256);

    // L2: split-K -> Cp (bf16); reduce -> Hb
    k_gemm<0, 0><<<dim3(32, KS), 256, 0, stream>>>(
        Ha, nullptr, W2, nullptr, Cp, nullptr, 4096, kchunk);
    k_reduce<<<1024, 256, 0, stream>>>(Cp, b2, Hb, nullptr, 4096, KS, 0);

    // L3: split-K -> Cp; reduce -> Ha
    k_gemm<0, 0><<<dim3(32, KS), 256, 0, stream>>>(
        Hb, nullptr, W3, nullptr, Cp, nullptr, 4096, kchunk);
    k_reduce<<<1024, 256, 0, stream>>>(Cp, b3, Ha, nullptr, 4096, KS, 0);

    // L4: N=256, split-K KS=32 (kchunk=128, nit=4) -> Cp; reduce+sigmoid -> pol
    k_gemm<0, 0><<<dim3(2, 32), 256, 0, stream>>>(
        Ha, nullptr, W4, nullptr, Cp, nullptr, 256, 128);
    k_reduce<<<64, 256, 0, stream>>>(Cp, b4, nullptr, pol, 256, 32, 1);

    // Power iteration + factored output
    k_power_out<<<1, 1024, 0, stream>>>(pol, Ts, outp);

    (void)in_sizes; (void)n_in; (void)out_size; (void)ws_size;
}